// Round 1
// baseline (226.797 us; speedup 1.0000x reference)
//
#include <hip/hip_runtime.h>

typedef __attribute__((ext_vector_type(8))) short short8;
typedef __attribute__((ext_vector_type(4))) float floatx4;

__device__ __forceinline__ unsigned short f2bf(float f) {
    union { float f; unsigned int u; } v; v.f = f;
    unsigned int r = (v.u + 0x7fffu + ((v.u >> 16) & 1u)) >> 16;
    return (unsigned short)r;
}

// ---------------------------------------------------------------------------
// T: ctrl [8,128,128,128] f32 NCHW -> ctrlT [8,128y,128x,128ci] bf16 NHWC
// ---------------------------------------------------------------------------
__global__ __launch_bounds__(256) void transpose_kernel(
    const float* __restrict__ ctrl, unsigned short* __restrict__ ctrlT)
{
    __shared__ unsigned short tile[64 * 66];
    const int t = threadIdx.x;
    const int x0 = blockIdx.x * 64, ci0 = blockIdx.y * 64;
    const int b = blockIdx.z >> 7, y = blockIdx.z & 127;
#pragma unroll
    for (int it = 0; it < 4; it++) {
        int ci_l = it * 16 + (t >> 4);
        int x_l = (t & 15) * 4;
        const float4 v = *(const float4*)&ctrl[(((size_t)b * 128 + ci0 + ci_l) * 128 + y) * 128 + x0 + x_l];
        tile[(x_l + 0) * 66 + ci_l] = f2bf(v.x);
        tile[(x_l + 1) * 66 + ci_l] = f2bf(v.y);
        tile[(x_l + 2) * 66 + ci_l] = f2bf(v.z);
        tile[(x_l + 3) * 66 + ci_l] = f2bf(v.w);
    }
    __syncthreads();
#pragma unroll
    for (int it = 0; it < 2; it++) {
        int x_l = it * 32 + (t >> 3);
        int ci_l = (t & 7) * 8;
        const unsigned int* p = (const unsigned int*)&tile[x_l * 66 + ci_l];
        uint4 u = make_uint4(p[0], p[1], p[2], p[3]);
        *(uint4*)&ctrlT[(((size_t)b * 128 + y) * 128 + x0 + x_l) * 128 + ci0 + ci_l] = u;
    }
}

// ---------------------------------------------------------------------------
// W-prep: w1 -> [c4=4][tap=9][co=64][ci=32] bf16 ; w2 -> [c4=2][tap=9][co=32][ci=32]
// ---------------------------------------------------------------------------
__global__ __launch_bounds__(256) void prep_w_kernel(
    const float* __restrict__ w1, const float* __restrict__ w2,
    unsigned short* __restrict__ w1p, unsigned short* __restrict__ w2p)
{
    int i = blockIdx.x * 256 + threadIdx.x;
    if (i < 4 * 9 * 64 * 32) {
        int ci = i & 31; int t2 = i >> 5; int co = t2 & 63; int t3 = t2 >> 6;
        int tap = t3 % 9; int c4 = t3 / 9;
        float v = 0.f;
        if (co < 50) v = w1[((size_t)co * 128 + c4 * 32 + ci) * 9 + tap];
        w1p[i] = f2bf(v);
    } else {
        int j = i - 4 * 9 * 64 * 32;
        int ci = j & 31; int t2 = j >> 5; int co = t2 & 31; int t3 = t2 >> 5;
        int tap = t3 % 9; int c4 = t3 / 9;
        int cig = c4 * 32 + ci;
        float v = 0.f;
        if (co < 18 && cig < 50) v = w2[((size_t)co * 50 + cig) * 9 + tap];
        w2p[j] = f2bf(v);
    }
}

// ---------------------------------------------------------------------------
// conv1 MFMA: M-tile 256 px (16x16), N = 64 co. Wave: 4 mt x 4 nt.
// grid (8,8,8); LDS 72 KB -> 2 blocks/CU.
// ---------------------------------------------------------------------------
__global__ __launch_bounds__(256) void conv1_mfma(
    const unsigned short* __restrict__ xT, const unsigned short* __restrict__ w1p,
    const float* __restrict__ b1, const float* __restrict__ gamma,
    const float* __restrict__ beta, const float* __restrict__ mean,
    const float* __restrict__ var, unsigned short* __restrict__ h)
{
    __shared__ unsigned short in_s[324 * 40];     // 18x18 px halo, 32 ci (pad 40)
    __shared__ unsigned short w_s[9 * 64 * 40];   // tap x co x 32 ci
    const int tid = threadIdx.x;
    const int x0 = blockIdx.x * 16, y0 = blockIdx.y * 16, b = blockIdx.z;
    const int wid = tid >> 6, lane = tid & 63;
    const int ln = lane & 15, q = lane >> 4;

    floatx4 acc[4][4];
#pragma unroll
    for (int mt = 0; mt < 4; mt++)
#pragma unroll
        for (int nt = 0; nt < 4; nt++) acc[mt][nt] = (floatx4)(0.f);

    for (int c4 = 0; c4 < 4; c4++) {
        // stage input: 324 px x 32 ci = 1296 uint4
        for (int i = tid; i < 1296; i += 256) {
            int p = i >> 2, g = i & 3;
            int gy = y0 + p / 18 - 1, gx = x0 + p % 18 - 1;
            uint4 v = make_uint4(0, 0, 0, 0);
            if (gy >= 0 && gy < 128 && gx >= 0 && gx < 128)
                v = *(const uint4*)&xT[(((size_t)b * 128 + gy) * 128 + gx) * 128 + c4 * 32 + g * 8];
            *(uint4*)&in_s[p * 40 + g * 8] = v;
        }
        // stage weights: 2304 uint4
#pragma unroll
        for (int it = 0; it < 9; it++) {
            int f = it * 256 + tid;
            int g = f & 3, co = (f >> 2) & 63, tap = f >> 8;
            uint4 v = *(const uint4*)&w1p[(((size_t)c4 * 9 + tap) * 64 + co) * 32 + g * 8];
            *(uint4*)&w_s[(tap * 64 + co) * 40 + g * 8] = v;
        }
        __syncthreads();

#pragma unroll
        for (int tap = 0; tap < 9; tap++) {
            const int dy = tap / 3, dx = tap % 3;
            short8 a[4];
#pragma unroll
            for (int mt = 0; mt < 4; mt++)
                a[mt] = *(const short8*)&in_s[((wid * 4 + mt + dy) * 18 + ln + dx) * 40 + q * 8];
#pragma unroll
            for (int nt = 0; nt < 4; nt++) {
                short8 bf = *(const short8*)&w_s[(tap * 64 + nt * 16 + ln) * 40 + q * 8];
#pragma unroll
                for (int mt = 0; mt < 4; mt++)
                    acc[mt][nt] = __builtin_amdgcn_mfma_f32_16x16x32_bf16(a[mt], bf, acc[mt][nt], 0, 0, 0);
            }
        }
        __syncthreads();
    }

#pragma unroll
    for (int nt = 0; nt < 4; nt++) {
        int co = nt * 16 + ln;
        bool real = co < 50;
        float sc = 0.f, mn = 0.f, bt = 0.f, bs = 0.f;
        if (real) {
            sc = gamma[co] * rsqrtf(var[co] + 1e-5f);
            mn = mean[co]; bt = beta[co]; bs = b1[co];
        }
#pragma unroll
        for (int mt = 0; mt < 4; mt++) {
            int gy = y0 + wid * 4 + mt;
#pragma unroll
            for (int r = 0; r < 4; r++) {
                int px = q * 4 + r;
                float v = 0.f;
                if (real) {
                    float tv = fmaxf(acc[mt][nt][r] + bs, 0.f);
                    v = (tv - mn) * sc + bt;
                }
                h[(((size_t)b * 128 + gy) * 128 + x0 + px) * 64 + co] = f2bf(v);
            }
        }
    }
}

// ---------------------------------------------------------------------------
// conv2 MFMA: M-tile 256 px, N = 32 (18 real). Wave: 4 mt x 2 nt. grid (8,8,8)
// ---------------------------------------------------------------------------
__global__ __launch_bounds__(256) void conv2_mfma(
    const unsigned short* __restrict__ hT, const unsigned short* __restrict__ w2p,
    const float* __restrict__ b2, float* __restrict__ cond)
{
    __shared__ unsigned short in_s[324 * 40];
    __shared__ unsigned short w_s[9 * 32 * 40];
    const int tid = threadIdx.x;
    const int x0 = blockIdx.x * 16, y0 = blockIdx.y * 16, b = blockIdx.z;
    const int wid = tid >> 6, lane = tid & 63;
    const int ln = lane & 15, q = lane >> 4;

    floatx4 acc[4][2];
#pragma unroll
    for (int mt = 0; mt < 4; mt++)
#pragma unroll
        for (int nt = 0; nt < 2; nt++) acc[mt][nt] = (floatx4)(0.f);

    for (int c4 = 0; c4 < 2; c4++) {
        for (int i = tid; i < 1296; i += 256) {
            int p = i >> 2, g = i & 3;
            int gy = y0 + p / 18 - 1, gx = x0 + p % 18 - 1;
            uint4 v = make_uint4(0, 0, 0, 0);
            if (gy >= 0 && gy < 128 && gx >= 0 && gx < 128)
                v = *(const uint4*)&hT[(((size_t)b * 128 + gy) * 128 + gx) * 64 + c4 * 32 + g * 8];
            *(uint4*)&in_s[p * 40 + g * 8] = v;
        }
#pragma unroll
        for (int it = 0; it < 5; it++) {
            int f = it * 256 + tid;
            if (f < 1152) {
                int g = f & 3, co = (f >> 2) & 31, tap = f >> 7;
                uint4 v = *(const uint4*)&w2p[(((size_t)c4 * 9 + tap) * 32 + co) * 32 + g * 8];
                *(uint4*)&w_s[(tap * 32 + co) * 40 + g * 8] = v;
            }
        }
        __syncthreads();

#pragma unroll
        for (int tap = 0; tap < 9; tap++) {
            const int dy = tap / 3, dx = tap % 3;
            short8 a[4];
#pragma unroll
            for (int mt = 0; mt < 4; mt++)
                a[mt] = *(const short8*)&in_s[((wid * 4 + mt + dy) * 18 + ln + dx) * 40 + q * 8];
#pragma unroll
            for (int nt = 0; nt < 2; nt++) {
                short8 bf = *(const short8*)&w_s[(tap * 32 + nt * 16 + ln) * 40 + q * 8];
#pragma unroll
                for (int mt = 0; mt < 4; mt++)
                    acc[mt][nt] = __builtin_amdgcn_mfma_f32_16x16x32_bf16(a[mt], bf, acc[mt][nt], 0, 0, 0);
            }
        }
        __syncthreads();
    }

#pragma unroll
    for (int nt = 0; nt < 2; nt++) {
        int co = nt * 16 + ln;
        if (co < 18) {
            float bs = b2[co];
#pragma unroll
            for (int mt = 0; mt < 4; mt++) {
                int gy = y0 + wid * 4 + mt;
#pragma unroll
                for (int r = 0; r < 4; r++) {
                    int px = q * 4 + r;
                    cond[(((size_t)b * 128 + gy) * 128 + x0 + px) * 18 + co] = acc[mt][nt][r] + bs;
                }
            }
        }
    }
}

// ---------------------------------------------------------------------------
// apply: rolling y-strip, occupancy-optimized.
// Strip = 16 rows (was 32); channels split into 2 groups of 3 via blockIdx.z.
// Thread = (x4 column, sub-row s). Out rows o_j = base + 4j + s (j=0..3).
// Row loads r_m = base + s + 4(m-1), m=0..5 -> 6 loads / 4 outputs (1.5x).
// 3-slot rolling accumulator, 3 channels.
// grid (2, 32, 16); block 256 = 64 x4 cols x 4 s. 1024 blocks = 4/CU.
// ---------------------------------------------------------------------------
__global__ __launch_bounds__(256) void apply_kernel(
    const float* __restrict__ img, const float* __restrict__ cond,
    float* __restrict__ out)
{
    const int tid = threadIdx.x;
    const int xl = tid & 63, s = tid >> 6;
    const int x4 = blockIdx.x * 64 + xl;
    const int base = blockIdx.y * 16;
    const int b = blockIdx.z >> 1, g = blockIdx.z & 1;
    const int cyb = base >> 2;

    float4 acc[3][3];
#pragma unroll
    for (int sl = 0; sl < 3; sl++)
#pragma unroll
        for (int c = 0; c < 3; c++) acc[sl][c] = make_float4(0.f, 0.f, 0.f, 0.f);

#pragma unroll
    for (int m = 0; m <= 5; m++) {
        const int r = base + s + 4 * (m - 1);
        const bool rok = (r >= 0) && (r < 512);   // wave-uniform (s = wave id)
        float4 v[3][3];
#pragma unroll
        for (int cc = 0; cc < 3; cc++)
#pragma unroll
            for (int i = 0; i < 3; i++) {
                int xx = x4 * 4 + i * 4 - 4;
                v[cc][i] = make_float4(0.f, 0.f, 0.f, 0.f);
                if (rok && xx >= 0 && xx < 512)
                    v[cc][i] = *(const float4*)&img[(((size_t)b * 6 + g * 3 + cc) * 512 + r) * 512 + xx];
            }
#pragma unroll
        for (int j = m - 2; j <= m; j++) {
            if (j >= 0 && j < 4) {
                const int jy = m - j;
                const int slot = j % 3;
                const float* cw = &cond[(((size_t)b * 128 + cyb + j) * 128 + x4) * 18 + g * 9];
#pragma unroll
                for (int i = 0; i < 3; i++) {
                    float wv = cw[i * 3 + jy];
#pragma unroll
                    for (int cc = 0; cc < 3; cc++) {
                        acc[slot][cc].x += v[cc][i].x * wv;
                        acc[slot][cc].y += v[cc][i].y * wv;
                        acc[slot][cc].z += v[cc][i].z * wv;
                        acc[slot][cc].w += v[cc][i].w * wv;
                    }
                }
            }
        }
        const int jd = m - 2;
        if (jd >= 0 && jd < 4) {
            const int o = base + 4 * jd + s;
            const int slot = jd % 3;
#pragma unroll
            for (int cc = 0; cc < 3; cc++) {
                *(float4*)&out[(((size_t)b * 6 + g * 3 + cc) * 512 + o) * 512 + x4 * 4] = acc[slot][cc];
                acc[slot][cc] = make_float4(0.f, 0.f, 0.f, 0.f);
            }
        }
    }
}

// ---------------------------------------------------------------------------
extern "C" void kernel_launch(void* const* d_in, const int* in_sizes, int n_in,
                              void* d_out, int out_size, void* d_ws, size_t ws_size,
                              hipStream_t stream)
{
    const float* img   = (const float*)d_in[0];
    const float* ctrl  = (const float*)d_in[1];
    const float* w1    = (const float*)d_in[2];
    const float* b1    = (const float*)d_in[3];
    const float* gamma = (const float*)d_in[4];
    const float* beta  = (const float*)d_in[5];
    const float* mean  = (const float*)d_in[6];
    const float* var   = (const float*)d_in[7];
    const float* w2    = (const float*)d_in[8];
    const float* b2    = (const float*)d_in[9];
    float* out = (float*)d_out;

    char* ws = (char*)d_ws;
    unsigned short* ctrlT = (unsigned short*)ws;                        // 33,554,432 B
    unsigned short* hbuf  = (unsigned short*)(ws + 33554432);           // 16,777,216 B
    float*          cond  = (float*)(ws + 50331648);                    //  9,437,184 B
    unsigned short* w1p   = (unsigned short*)(ws + 59768832);           //    147,456 B
    unsigned short* w2p   = (unsigned short*)(ws + 59916288);           //     36,864 B

    transpose_kernel<<<dim3(2, 2, 1024), 256, 0, stream>>>(ctrl, ctrlT);
    prep_w_kernel<<<360, 256, 0, stream>>>(w1, w2, w1p, w2p);
    conv1_mfma<<<dim3(8, 8, 8), 256, 0, stream>>>(ctrlT, w1p, b1, gamma, beta, mean, var, hbuf);
    conv2_mfma<<<dim3(8, 8, 8), 256, 0, stream>>>(hbuf, w2p, b2, cond);
    apply_kernel<<<dim3(2, 32, 16), 256, 0, stream>>>(img, cond, out);
}

// Round 2
// 225.633 us; speedup vs baseline: 1.0052x; 1.0052x over previous
//
#include <hip/hip_runtime.h>

typedef __attribute__((ext_vector_type(8))) short short8;
typedef __attribute__((ext_vector_type(4))) float floatx4;

__device__ __forceinline__ unsigned short f2bf(float f) {
    union { float f; unsigned int u; } v; v.f = f;
    unsigned int r = (v.u + 0x7fffu + ((v.u >> 16) & 1u)) >> 16;
    return (unsigned short)r;
}

__device__ __forceinline__ float4 shfl4(float4 v, int srcLane) {
    float4 r;
    r.x = __shfl(v.x, srcLane, 64);
    r.y = __shfl(v.y, srcLane, 64);
    r.z = __shfl(v.z, srcLane, 64);
    r.w = __shfl(v.w, srcLane, 64);
    return r;
}

// ---------------------------------------------------------------------------
// T: ctrl [8,128,128,128] f32 NCHW -> ctrlT [8,128y,128x,128ci] bf16 NHWC
// ---------------------------------------------------------------------------
__global__ __launch_bounds__(256) void transpose_kernel(
    const float* __restrict__ ctrl, unsigned short* __restrict__ ctrlT)
{
    __shared__ unsigned short tile[64 * 66];
    const int t = threadIdx.x;
    const int x0 = blockIdx.x * 64, ci0 = blockIdx.y * 64;
    const int b = blockIdx.z >> 7, y = blockIdx.z & 127;
#pragma unroll
    for (int it = 0; it < 4; it++) {
        int ci_l = it * 16 + (t >> 4);
        int x_l = (t & 15) * 4;
        const float4 v = *(const float4*)&ctrl[(((size_t)b * 128 + ci0 + ci_l) * 128 + y) * 128 + x0 + x_l];
        tile[(x_l + 0) * 66 + ci_l] = f2bf(v.x);
        tile[(x_l + 1) * 66 + ci_l] = f2bf(v.y);
        tile[(x_l + 2) * 66 + ci_l] = f2bf(v.z);
        tile[(x_l + 3) * 66 + ci_l] = f2bf(v.w);
    }
    __syncthreads();
#pragma unroll
    for (int it = 0; it < 2; it++) {
        int x_l = it * 32 + (t >> 3);
        int ci_l = (t & 7) * 8;
        const unsigned int* p = (const unsigned int*)&tile[x_l * 66 + ci_l];
        uint4 u = make_uint4(p[0], p[1], p[2], p[3]);
        *(uint4*)&ctrlT[(((size_t)b * 128 + y) * 128 + x0 + x_l) * 128 + ci0 + ci_l] = u;
    }
}

// ---------------------------------------------------------------------------
// W-prep: w1 -> [c4=4][tap=9][co=64][ci=32] bf16 ; w2 -> [c4=2][tap=9][co=32][ci=32]
// ---------------------------------------------------------------------------
__global__ __launch_bounds__(256) void prep_w_kernel(
    const float* __restrict__ w1, const float* __restrict__ w2,
    unsigned short* __restrict__ w1p, unsigned short* __restrict__ w2p)
{
    int i = blockIdx.x * 256 + threadIdx.x;
    if (i < 4 * 9 * 64 * 32) {
        int ci = i & 31; int t2 = i >> 5; int co = t2 & 63; int t3 = t2 >> 6;
        int tap = t3 % 9; int c4 = t3 / 9;
        float v = 0.f;
        if (co < 50) v = w1[((size_t)co * 128 + c4 * 32 + ci) * 9 + tap];
        w1p[i] = f2bf(v);
    } else {
        int j = i - 4 * 9 * 64 * 32;
        int ci = j & 31; int t2 = j >> 5; int co = t2 & 31; int t3 = t2 >> 5;
        int tap = t3 % 9; int c4 = t3 / 9;
        int cig = c4 * 32 + ci;
        float v = 0.f;
        if (co < 18 && cig < 50) v = w2[((size_t)co * 50 + cig) * 9 + tap];
        w2p[j] = f2bf(v);
    }
}

// ---------------------------------------------------------------------------
// conv1 MFMA: M-tile 256 px (16x16), N = 64 co. Wave: 4 mt x 4 nt.
// grid (8,8,8); LDS 72 KB -> 2 blocks/CU.
// ---------------------------------------------------------------------------
__global__ __launch_bounds__(256) void conv1_mfma(
    const unsigned short* __restrict__ xT, const unsigned short* __restrict__ w1p,
    const float* __restrict__ b1, const float* __restrict__ gamma,
    const float* __restrict__ beta, const float* __restrict__ mean,
    const float* __restrict__ var, unsigned short* __restrict__ h)
{
    __shared__ unsigned short in_s[324 * 40];     // 18x18 px halo, 32 ci (pad 40)
    __shared__ unsigned short w_s[9 * 64 * 40];   // tap x co x 32 ci
    const int tid = threadIdx.x;
    const int x0 = blockIdx.x * 16, y0 = blockIdx.y * 16, b = blockIdx.z;
    const int wid = tid >> 6, lane = tid & 63;
    const int ln = lane & 15, q = lane >> 4;

    floatx4 acc[4][4];
#pragma unroll
    for (int mt = 0; mt < 4; mt++)
#pragma unroll
        for (int nt = 0; nt < 4; nt++) acc[mt][nt] = (floatx4)(0.f);

    for (int c4 = 0; c4 < 4; c4++) {
        // stage input: 324 px x 32 ci = 1296 uint4
        for (int i = tid; i < 1296; i += 256) {
            int p = i >> 2, g = i & 3;
            int gy = y0 + p / 18 - 1, gx = x0 + p % 18 - 1;
            uint4 v = make_uint4(0, 0, 0, 0);
            if (gy >= 0 && gy < 128 && gx >= 0 && gx < 128)
                v = *(const uint4*)&xT[(((size_t)b * 128 + gy) * 128 + gx) * 128 + c4 * 32 + g * 8];
            *(uint4*)&in_s[p * 40 + g * 8] = v;
        }
        // stage weights: 2304 uint4
#pragma unroll
        for (int it = 0; it < 9; it++) {
            int f = it * 256 + tid;
            int g = f & 3, co = (f >> 2) & 63, tap = f >> 8;
            uint4 v = *(const uint4*)&w1p[(((size_t)c4 * 9 + tap) * 64 + co) * 32 + g * 8];
            *(uint4*)&w_s[(tap * 64 + co) * 40 + g * 8] = v;
        }
        __syncthreads();

#pragma unroll
        for (int tap = 0; tap < 9; tap++) {
            const int dy = tap / 3, dx = tap % 3;
            short8 a[4];
#pragma unroll
            for (int mt = 0; mt < 4; mt++)
                a[mt] = *(const short8*)&in_s[((wid * 4 + mt + dy) * 18 + ln + dx) * 40 + q * 8];
#pragma unroll
            for (int nt = 0; nt < 4; nt++) {
                short8 bf = *(const short8*)&w_s[(tap * 64 + nt * 16 + ln) * 40 + q * 8];
#pragma unroll
                for (int mt = 0; mt < 4; mt++)
                    acc[mt][nt] = __builtin_amdgcn_mfma_f32_16x16x32_bf16(a[mt], bf, acc[mt][nt], 0, 0, 0);
            }
        }
        __syncthreads();
    }

#pragma unroll
    for (int nt = 0; nt < 4; nt++) {
        int co = nt * 16 + ln;
        bool real = co < 50;
        float sc = 0.f, mn = 0.f, bt = 0.f, bs = 0.f;
        if (real) {
            sc = gamma[co] * rsqrtf(var[co] + 1e-5f);
            mn = mean[co]; bt = beta[co]; bs = b1[co];
        }
#pragma unroll
        for (int mt = 0; mt < 4; mt++) {
            int gy = y0 + wid * 4 + mt;
#pragma unroll
            for (int r = 0; r < 4; r++) {
                int px = q * 4 + r;
                float v = 0.f;
                if (real) {
                    float tv = fmaxf(acc[mt][nt][r] + bs, 0.f);
                    v = (tv - mn) * sc + bt;
                }
                h[(((size_t)b * 128 + gy) * 128 + x0 + px) * 64 + co] = f2bf(v);
            }
        }
    }
}

// ---------------------------------------------------------------------------
// conv2 MFMA: M-tile 256 px, N = 32 (18 real). Wave: 4 mt x 2 nt. grid (8,8,8)
// Epilogue writes cond in apply-friendly layout:
//   cond[b][cy][cx][24] where pos = g*12 + jy*4 + i  (k = i*3 + jy, co = g*9+k)
//   -> apply reads one aligned float4 per (m,j): weights for i=0..2 at fixed jy.
// ---------------------------------------------------------------------------
__global__ __launch_bounds__(256) void conv2_mfma(
    const unsigned short* __restrict__ hT, const unsigned short* __restrict__ w2p,
    const float* __restrict__ b2, float* __restrict__ cond)
{
    __shared__ unsigned short in_s[324 * 40];
    __shared__ unsigned short w_s[9 * 32 * 40];
    const int tid = threadIdx.x;
    const int x0 = blockIdx.x * 16, y0 = blockIdx.y * 16, b = blockIdx.z;
    const int wid = tid >> 6, lane = tid & 63;
    const int ln = lane & 15, q = lane >> 4;

    floatx4 acc[4][2];
#pragma unroll
    for (int mt = 0; mt < 4; mt++)
#pragma unroll
        for (int nt = 0; nt < 2; nt++) acc[mt][nt] = (floatx4)(0.f);

    for (int c4 = 0; c4 < 2; c4++) {
        for (int i = tid; i < 1296; i += 256) {
            int p = i >> 2, g = i & 3;
            int gy = y0 + p / 18 - 1, gx = x0 + p % 18 - 1;
            uint4 v = make_uint4(0, 0, 0, 0);
            if (gy >= 0 && gy < 128 && gx >= 0 && gx < 128)
                v = *(const uint4*)&hT[(((size_t)b * 128 + gy) * 128 + gx) * 64 + c4 * 32 + g * 8];
            *(uint4*)&in_s[p * 40 + g * 8] = v;
        }
#pragma unroll
        for (int it = 0; it < 5; it++) {
            int f = it * 256 + tid;
            if (f < 1152) {
                int g = f & 3, co = (f >> 2) & 31, tap = f >> 7;
                uint4 v = *(const uint4*)&w2p[(((size_t)c4 * 9 + tap) * 32 + co) * 32 + g * 8];
                *(uint4*)&w_s[(tap * 32 + co) * 40 + g * 8] = v;
            }
        }
        __syncthreads();

#pragma unroll
        for (int tap = 0; tap < 9; tap++) {
            const int dy = tap / 3, dx = tap % 3;
            short8 a[4];
#pragma unroll
            for (int mt = 0; mt < 4; mt++)
                a[mt] = *(const short8*)&in_s[((wid * 4 + mt + dy) * 18 + ln + dx) * 40 + q * 8];
#pragma unroll
            for (int nt = 0; nt < 2; nt++) {
                short8 bf = *(const short8*)&w_s[(tap * 32 + nt * 16 + ln) * 40 + q * 8];
#pragma unroll
                for (int mt = 0; mt < 4; mt++)
                    acc[mt][nt] = __builtin_amdgcn_mfma_f32_16x16x32_bf16(a[mt], bf, acc[mt][nt], 0, 0, 0);
            }
        }
        __syncthreads();
    }

#pragma unroll
    for (int nt = 0; nt < 2; nt++) {
        int co = nt * 16 + ln;
        if (co < 18) {
            float bs = b2[co];
            int gch = co / 9, k = co % 9;
            int iw = k / 3, jy = k % 3;
            int pos = gch * 12 + jy * 4 + iw;
#pragma unroll
            for (int mt = 0; mt < 4; mt++) {
                int gy = y0 + wid * 4 + mt;
#pragma unroll
                for (int r = 0; r < 4; r++) {
                    int px = q * 4 + r;
                    cond[(((size_t)b * 128 + gy) * 128 + x0 + px) * 24 + pos] = acc[mt][nt][r] + bs;
                }
            }
        }
    }
}

// ---------------------------------------------------------------------------
// apply v2: rolling y-strip, latency-optimized.
//  - each lane loads only its OWN float4 per row/channel; left/right neighbor
//    float4s come from wave shuffles (lane +/-1); edge lanes (xl=0/63) get one
//    predicated extra load.
//  - cond weights: one aligned float4 per (m,j) via the [g][jy][4] layout.
//  - software pipeline: row m+1 loads issued before row m compute.
// grid (2, 32, 16); block 256 = 64 x4-cols x 4 s (s = wave id).
// ---------------------------------------------------------------------------
__global__ __launch_bounds__(256) void apply_kernel(
    const float* __restrict__ img, const float* __restrict__ cond,
    float* __restrict__ out)
{
    const int tid = threadIdx.x;
    const int xl = tid & 63, s = tid >> 6;
    const int x4 = blockIdx.x * 64 + xl;
    const int base = blockIdx.y * 16;
    const int b = blockIdx.z >> 1, g = blockIdx.z & 1;
    const int cyb = base >> 2;
    const int laneL = (xl + 63) & 63;
    const int laneR = (xl + 1) & 63;
    const bool isL = (xl == 0), isR = (xl == 63);

    const float* imgc[3];
#pragma unroll
    for (int cc = 0; cc < 3; cc++)
        imgc[cc] = &img[(((size_t)b * 6 + g * 3 + cc) * 512) * 512];

    float4 acc[3][3];   // [slot][channel]
#pragma unroll
    for (int sl = 0; sl < 3; sl++)
#pragma unroll
        for (int c = 0; c < 3; c++) acc[sl][c] = make_float4(0.f, 0.f, 0.f, 0.f);

    float4 vc[3], ec[3], vn[3], en[3];

    auto load_m = [&](int m, float4 vv[3], float4 ee[3]) {
        const int r = base + s + 4 * (m - 1);
        if (r >= 0 && r < 512) {                       // wave-uniform
            const int xo = x4 * 4;
            const int xe = isL ? xo - 4 : xo + 4;
            const bool eok = (isL && x4 > 0) || (isR && x4 < 127);
#pragma unroll
            for (int cc = 0; cc < 3; cc++) {
                const float* rp = imgc[cc] + (size_t)r * 512;
                vv[cc] = *(const float4*)&rp[xo];
                ee[cc] = make_float4(0.f, 0.f, 0.f, 0.f);
                if (eok) ee[cc] = *(const float4*)&rp[xe];
            }
        } else {
#pragma unroll
            for (int cc = 0; cc < 3; cc++) {
                vv[cc] = make_float4(0.f, 0.f, 0.f, 0.f);
                ee[cc] = make_float4(0.f, 0.f, 0.f, 0.f);
            }
        }
    };

    load_m(0, vc, ec);

#pragma unroll
    for (int m = 0; m <= 5; m++) {
        if (m < 5) load_m(m + 1, vn, en);

        const int jlo = (m - 2 > 0) ? (m - 2) : 0;
        const int jhi = (m < 3) ? m : 3;

        // cond weights for active j's: one aligned float4 each
        float4 wv[3];
#pragma unroll
        for (int j = 0; j < 4; j++) {
            if (j >= jlo && j <= jhi) {
                const int jy = m - j;
                wv[j - jlo] = *(const float4*)&cond[
                    (((size_t)b * 128 + cyb + j) * 128 + x4) * 24 + g * 12 + jy * 4];
            }
        }

        // neighbor float4s via wave shuffle (+ edge fixup)
        float4 vL[3], vR[3];
#pragma unroll
        for (int cc = 0; cc < 3; cc++) {
            vL[cc] = shfl4(vc[cc], laneL);
            vR[cc] = shfl4(vc[cc], laneR);
            if (isL) vL[cc] = ec[cc];
            if (isR) vR[cc] = ec[cc];
        }

#pragma unroll
        for (int j = 0; j < 4; j++) {
            if (j >= jlo && j <= jhi) {
                const int slot = j % 3;
                const float4 w = wv[j - jlo];
#pragma unroll
                for (int cc = 0; cc < 3; cc++) {
                    acc[slot][cc].x += vL[cc].x * w.x + vc[cc].x * w.y + vR[cc].x * w.z;
                    acc[slot][cc].y += vL[cc].y * w.x + vc[cc].y * w.y + vR[cc].y * w.z;
                    acc[slot][cc].z += vL[cc].z * w.x + vc[cc].z * w.y + vR[cc].z * w.z;
                    acc[slot][cc].w += vL[cc].w * w.x + vc[cc].w * w.y + vR[cc].w * w.z;
                }
            }
        }

        const int jd = m - 2;
        if (jd >= 0) {
            const int o = base + 4 * jd + s;
            const int slot = jd % 3;
#pragma unroll
            for (int cc = 0; cc < 3; cc++) {
                *(float4*)&out[((((size_t)b * 6 + g * 3 + cc) * 512) + o) * 512 + x4 * 4] = acc[slot][cc];
                acc[slot][cc] = make_float4(0.f, 0.f, 0.f, 0.f);
            }
        }

        if (m < 5) {
#pragma unroll
            for (int cc = 0; cc < 3; cc++) { vc[cc] = vn[cc]; ec[cc] = en[cc]; }
        }
    }
}

// ---------------------------------------------------------------------------
extern "C" void kernel_launch(void* const* d_in, const int* in_sizes, int n_in,
                              void* d_out, int out_size, void* d_ws, size_t ws_size,
                              hipStream_t stream)
{
    const float* img   = (const float*)d_in[0];
    const float* ctrl  = (const float*)d_in[1];
    const float* w1    = (const float*)d_in[2];
    const float* b1    = (const float*)d_in[3];
    const float* gamma = (const float*)d_in[4];
    const float* beta  = (const float*)d_in[5];
    const float* mean  = (const float*)d_in[6];
    const float* var   = (const float*)d_in[7];
    const float* w2    = (const float*)d_in[8];
    const float* b2    = (const float*)d_in[9];
    float* out = (float*)d_out;

    char* ws = (char*)d_ws;
    // cond reuses the ctrlT region: ctrlT is dead after conv1, cond is written
    // by conv2 (stream-ordered after conv1) and read only by apply.
    unsigned short* ctrlT = (unsigned short*)ws;                        // 33,554,432 B
    float*          cond  = (float*)ws;                                 // 12,582,912 B (overlap)
    unsigned short* hbuf  = (unsigned short*)(ws + 33554432);           // 16,777,216 B
    unsigned short* w1p   = (unsigned short*)(ws + 50331648);           //    147,456 B
    unsigned short* w2p   = (unsigned short*)(ws + 50479104);           //     36,864 B

    transpose_kernel<<<dim3(2, 2, 1024), 256, 0, stream>>>(ctrl, ctrlT);
    prep_w_kernel<<<360, 256, 0, stream>>>(w1, w2, w1p, w2p);
    conv1_mfma<<<dim3(8, 8, 8), 256, 0, stream>>>(ctrlT, w1p, b1, gamma, beta, mean, var, hbuf);
    conv2_mfma<<<dim3(8, 8, 8), 256, 0, stream>>>(hbuf, w2p, b2, cond);
    apply_kernel<<<dim3(2, 32, 16), 256, 0, stream>>>(img, cond, out);
}